// Round 9
// baseline (199.660 us; speedup 1.0000x reference)
//
#include <hip/hip_runtime.h>
#include <math.h>

#define N_NODES 8192
#define N3      24576              // N_NODES * 3
#define LR_C 0.01f
#define EPS_C 1e-6f
#define HASH_SLOTS (1u << 20)      // 4 MiB
#define HEMPTY 0xFFFFFFFFu
#define NB_SC 64                   // corr-histogram blocks
#define NB_DG 64                   // degree-histogram blocks
#define NB_LP 64                   // laplacian-histogram blocks

// =============== K_A: corr LDS-hist (blk 0-63) || hash clear (blk 64-319) ====
__global__ __launch_bounds__(512) void kA_corr_hashclear(
        const float* __restrict__ x0, const int* __restrict__ dist_idx,
        const float* __restrict__ dist_target,
        float* __restrict__ corr_part, uint4* __restrict__ hash4, int K) {
    __shared__ __align__(16) float smf[N3];          // 96 KiB
    int bid = blockIdx.x, tid = threadIdx.x;
    if (bid < NB_SC) {
        for (int t = tid; t < N3; t += 512) smf[t] = 0.f;
        __syncthreads();
        int per = (K + NB_SC - 1) / NB_SC;           // 1024
        int base = bid * per;
        for (int kk = tid; kk < per; kk += 512) {
            int k = base + kk;
            if (k >= K) break;
            int i = dist_idx[2 * k], j = dist_idx[2 * k + 1];
            float ax = x0[3 * i], ay = x0[3 * i + 1], az = x0[3 * i + 2];
            float bx = x0[3 * j], by = x0[3 * j + 1], bz = x0[3 * j + 2];
            float vx = ax - bx, vy = ay - by, vz = az - bz;
            float dist = sqrtf(vx * vx + vy * vy + vz * vz + 1e-12f);
            bool valid = (dist > EPS_C) && (i != j);
            float coef = valid ? (LR_C * 0.5f) * (dist - dist_target[k]) / dist
                               : 0.0f;
            if (coef != 0.0f) {
                float cx = coef * vx, cy = coef * vy, cz = coef * vz;
                atomicAdd(&smf[3 * i],     -cx);
                atomicAdd(&smf[3 * i + 1], -cy);
                atomicAdd(&smf[3 * i + 2], -cz);
                atomicAdd(&smf[3 * j],      cx);
                atomicAdd(&smf[3 * j + 1],  cy);
                atomicAdd(&smf[3 * j + 2],  cz);
            }
        }
        __syncthreads();
        float* dst = corr_part + (size_t)bid * N3;
        for (int t = tid; t < N3; t += 512) dst[t] = smf[t];
    } else {
        // 256 blocks clear 262144 uint4: 1024 per block, 2 per thread
        int base = (bid - NB_SC) * 1024;
        hash4[base + tid]       = make_uint4(HEMPTY, HEMPTY, HEMPTY, HEMPTY);
        hash4[base + tid + 512] = make_uint4(HEMPTY, HEMPTY, HEMPTY, HEMPTY);
    }
}

// =============== K_B: x1 reduce (blk 0-95) || hash CAS flags (blk 96-1119) ==
__global__ __launch_bounds__(256) void kB_x1_hashflags(
        const float* __restrict__ pos, const float* __restrict__ corr_part,
        float* __restrict__ x1, const int* __restrict__ edge_index,
        unsigned int* __restrict__ hash, unsigned char* __restrict__ flags,
        int E) {
    int bid = blockIdx.x, tid = threadIdx.x;
    if (bid < 96) {
        int e = bid * 256 + tid;                     // 24576 elems
        float s = pos[e];
        #pragma unroll 8
        for (int q = 0; q < NB_SC; ++q) s += corr_part[(size_t)q * N3 + e];
        x1[e] = s;
    } else {
        int k = (bid - 96) * 256 + tid;
        if (k >= E) return;
        int a = edge_index[k];
        int b = edge_index[E + k];
        a = min(max(a, 0), N_NODES - 1);
        b = min(max(b, 0), N_NODES - 1);
        unsigned int key = ((unsigned)a << 13) | (unsigned)b;   // 26 bits
        unsigned int h = (key * 2654435761u) >> 12;             // [0, 2^20)
        bool unique = false;
        while (true) {
            unsigned int old = atomicCAS(&hash[h], HEMPTY, key);
            if (old == HEMPTY) { unique = true; break; }
            if (old == key)    { break; }
            h = (h + 1) & (HASH_SLOTS - 1);
        }
        flags[k] = unique ? 1 : 0;
    }
}

// =============== K_C: repulsion (blk 0-511, 2 rows/thread) || deg (512-575) ==
__global__ __launch_bounds__(256) void kC_rep_deg(
        const float* __restrict__ x1, const float* __restrict__ min_dist,
        float4* __restrict__ rep_part, const int* __restrict__ edge_index,
        const unsigned char* __restrict__ flags, int* __restrict__ deg_part,
        int E) {
    __shared__ __align__(16) unsigned char smu[32768];   // 32 KiB union
    int bid = blockIdx.x, tid = threadIdx.x;
    if (bid < 512) {
        float4* pj = (float4*)smu;                   // 4 KiB j-tile
        int ic = bid >> 5;                           // 0..15 (512 rows each)
        int jc = bid & 31;                           // 0..31 (256 cols each)
        int jbase = jc << 8;
        {
            int j = jbase + tid;
            float a = x1[3 * j], b = x1[3 * j + 1], c = x1[3 * j + 2];
            pj[tid] = make_float4(a, b, c, a * a + b * b + c * c);
        }
        __syncthreads();
        int i0 = (ic << 9) + tid;
        int i1 = i0 + 256;
        float x0v = x1[3 * i0], y0v = x1[3 * i0 + 1], z0v = x1[3 * i0 + 2];
        float x1v = x1[3 * i1], y1v = x1[3 * i1 + 1], z1v = x1[3 * i1 + 2];
        float sq0 = x0v * x0v + y0v * y0v + z0v * z0v;
        float sq1 = x1v * x1v + y1v * y1v + z1v * z1v;
        float md = min_dist[0];
        const float c0 = 0.5f * LR_C;                // 0.005
        float c1 = c0 * md;
        int di0 = i0 - jbase, di1 = i1 - jbase;      // self slots (may be OOR)
        float S0 = 0.f, ax0 = 0.f, ay0 = 0.f, az0 = 0.f;
        float S1 = 0.f, ax1 = 0.f, ay1 = 0.f, az1 = 0.f;
        #pragma unroll 4
        for (int jj = 0; jj < 256; ++jj) {
            float4 q = pj[jj];
            float dot0 = fmaf(x0v, q.x, fmaf(y0v, q.y, z0v * q.z));
            float d20 = fmaf(-2.0f, dot0, sq0 + q.w);
            float r0 = __builtin_amdgcn_rsqf(fmaxf(d20, 1e-12f));
            float w0 = fmaxf(fmaf(c1, r0, -c0), 0.0f);       // >0 iff d < md
            w0 = (d20 > 1e-12f && jj != di0) ? w0 : 0.0f;
            S0 += w0;
            ax0 = fmaf(w0, q.x, ax0); ay0 = fmaf(w0, q.y, ay0); az0 = fmaf(w0, q.z, az0);
            float dot1 = fmaf(x1v, q.x, fmaf(y1v, q.y, z1v * q.z));
            float d21 = fmaf(-2.0f, dot1, sq1 + q.w);
            float r1 = __builtin_amdgcn_rsqf(fmaxf(d21, 1e-12f));
            float w1 = fmaxf(fmaf(c1, r1, -c0), 0.0f);
            w1 = (d21 > 1e-12f && jj != di1) ? w1 : 0.0f;
            S1 += w1;
            ax1 = fmaf(w1, q.x, ax1); ay1 = fmaf(w1, q.y, ay1); az1 = fmaf(w1, q.z, az1);
        }
        rep_part[(size_t)jc * N_NODES + i0] = make_float4(ax0, ay0, az0, S0);
        rep_part[(size_t)jc * N_NODES + i1] = make_float4(ax1, ay1, az1, S1);
    } else {
        int* hist = (int*)smu;                       // 32 KiB histogram
        for (int t = tid; t < N_NODES; t += 256) hist[t] = 0;
        __syncthreads();
        int b = bid - 512;
        int per = (E + NB_DG - 1) / NB_DG;           // 4096
        int base = b * per;
        for (int kk = tid; kk < per; kk += 256) {
            int k = base + kk;
            if (k >= E) break;
            if (!flags[k]) continue;
            int a = edge_index[k];
            int c = edge_index[E + k];
            a = min(max(a, 0), N_NODES - 1);
            c = min(max(c, 0), N_NODES - 1);
            atomicAdd(&hist[a], 1);
            atomicAdd(&hist[c], 1);
        }
        __syncthreads();
        int* dst = deg_part + (size_t)b * N_NODES;
        for (int t = tid; t < N_NODES; t += 256) dst[t] = hist[t];
    }
}

// =============== K_D: finalize x2/out/z4 (32 blocks) ========================
__global__ __launch_bounds__(256) void kD_finalize(
        const float* __restrict__ x1, const float4* __restrict__ rep_part,
        const int* __restrict__ deg_part,
        float* __restrict__ out_x, float4* __restrict__ z4) {
    int row = blockIdx.x * 256 + threadIdx.x;        // 8192 rows
    float S = 0.f, ax = 0.f, ay = 0.f, az = 0.f;
    #pragma unroll 8
    for (int c = 0; c < 32; ++c) {
        float4 q = rep_part[(size_t)c * N_NODES + row];
        ax += q.x; ay += q.y; az += q.z; S += q.w;
    }
    int d = 0;
    #pragma unroll 8
    for (int q = 0; q < NB_DG; ++q) d += deg_part[(size_t)q * N_NODES + row];
    float xi = x1[3 * row], yi = x1[3 * row + 1], zi = x1[3 * row + 2];
    float ox = xi + xi * S - ax;
    float oy = yi + yi * S - ay;
    float oz = zi + zi * S - az;
    out_x[3 * row] = ox; out_x[3 * row + 1] = oy; out_x[3 * row + 2] = oz;
    float dv = (d == 0) ? 0.0f : 1.0f / sqrtf((float)d + EPS_C);
    z4[row] = make_float4(dv * ox, dv * oy, dv * oz, dv);
}

// =============== K_E: laplacian LDS-hist (64 blocks x 512) ==================
__global__ __launch_bounds__(512) void kE_lap_hist(
        const int* __restrict__ edge_index, const unsigned char* __restrict__ flags,
        const float4* __restrict__ z4, float* __restrict__ lap_part, int E) {
    __shared__ __align__(16) float acc[N3];          // 96 KiB
    int bid = blockIdx.x, tid = threadIdx.x;
    for (int t = tid; t < N3; t += 512) acc[t] = 0.f;
    __syncthreads();
    int per = (E + NB_LP - 1) / NB_LP;               // 4096
    int base = bid * per;
    for (int kk = tid; kk < per; kk += 512) {
        int k = base + kk;
        if (k >= E) break;
        if (!flags[k]) continue;
        int a = edge_index[k];
        int c = edge_index[E + k];
        a = min(max(a, 0), N_NODES - 1);
        c = min(max(c, 0), N_NODES - 1);
        float4 zc = z4[c];
        float4 za = z4[a];
        atomicAdd(&acc[3 * a],     zc.x);
        atomicAdd(&acc[3 * a + 1], zc.y);
        atomicAdd(&acc[3 * a + 2], zc.z);
        atomicAdd(&acc[3 * c],     za.x);
        atomicAdd(&acc[3 * c + 1], za.y);
        atomicAdd(&acc[3 * c + 2], za.z);
    }
    __syncthreads();
    float* dst = lap_part + (size_t)bid * N3;
    for (int t = tid; t < N3; t += 512) dst[t] = acc[t];
}

// =============== K_F: curvature (32 blocks) =================================
__global__ __launch_bounds__(256) void kF_curvature(
        const float* __restrict__ out_x, const float4* __restrict__ z4,
        const float* __restrict__ lap_part, float* __restrict__ out_curv) {
    int row = blockIdx.x * 256 + threadIdx.x;
    float lx = 0.f, ly = 0.f, lz = 0.f;
    #pragma unroll 8
    for (int q = 0; q < NB_LP; ++q) {
        const float* src = lap_part + (size_t)q * N3 + 3 * row;
        lx += src[0]; ly += src[1]; lz += src[2];
    }
    float dv = z4[row].w;
    float Lx = out_x[3 * row]     - dv * lx;
    float Ly = out_x[3 * row + 1] - dv * ly;
    float Lz = out_x[3 * row + 2] - dv * lz;
    out_curv[row] = sqrtf(Lx * Lx + Ly * Ly + Lz * Lz + 1e-12f);
}

extern "C" void kernel_launch(void* const* d_in, const int* in_sizes, int n_in,
                              void* d_out, int out_size, void* d_ws, size_t ws_size,
                              hipStream_t stream) {
    const float* positions   = (const float*)d_in[0];
    const int*   edge_index  = (const int*)d_in[1];
    const int*   dist_idx    = (const int*)d_in[2];
    const float* dist_target = (const float*)d_in[3];
    const float* min_dist    = (const float*)d_in[4];
    float* out = (float*)d_out;

    const int E = in_sizes[1] / 2;   // 262144
    const int K = in_sizes[2] / 2;   // 65536

    // ---- workspace layout (16B aligned), lifetime overlays ----
    char* ws = (char*)d_ws;
    const size_t X1_OFF   = 0;                                   //  96 KiB
    const size_t Z4_OFF   = X1_OFF + (size_t)N3 * 4;             // 128 KiB
    const size_t FLAG_OFF = Z4_OFF + (size_t)N_NODES * 16;       // 256 KiB
    const size_t R1_OFF   = FLAG_OFF + (size_t)E;                //   6 MiB
    const size_t R2_OFF   = R1_OFF + (size_t)NB_SC * N3 * 4;     //   6 MiB

    float* x1            = (float*)(ws + X1_OFF);
    float4* z4           = (float4*)(ws + Z4_OFF);
    unsigned char* flags = (unsigned char*)(ws + FLAG_OFF);
    float* corr_part     = (float*)(ws + R1_OFF);
    float4* rep_part     = (float4*)(ws + R1_OFF);               // overlay
    unsigned int* hash   = (unsigned int*)(ws + R2_OFF);
    int* deg_part        = (int*)(ws + R2_OFF + (size_t)HASH_SLOTS * 4);
    float* lap_part      = (float*)(ws + R2_OFF);                // overlay

    // ===== DIFFERENTIAL-TIMING ROUND: every idempotent kernel dispatched 2x.
    // dur(R9) - dur(R8) = kA + kC + kD + kE + kF + 5*gap.
    // kB is NOT duplicated (CAS re-run on populated hash would corrupt flags).

    kA_corr_hashclear<<<NB_SC + 256, 512, 0, stream>>>(
        positions, dist_idx, dist_target, corr_part, (uint4*)hash, K);
    kA_corr_hashclear<<<NB_SC + 256, 512, 0, stream>>>(
        positions, dist_idx, dist_target, corr_part, (uint4*)hash, K);

    kB_x1_hashflags<<<96 + (E + 255) / 256, 256, 0, stream>>>(
        positions, corr_part, x1, edge_index, hash, flags, E);

    kC_rep_deg<<<512 + NB_DG, 256, 0, stream>>>(
        x1, min_dist, rep_part, edge_index, flags, deg_part, E);
    kC_rep_deg<<<512 + NB_DG, 256, 0, stream>>>(
        x1, min_dist, rep_part, edge_index, flags, deg_part, E);

    kD_finalize<<<32, 256, 0, stream>>>(x1, rep_part, deg_part, out, z4);
    kD_finalize<<<32, 256, 0, stream>>>(x1, rep_part, deg_part, out, z4);

    kE_lap_hist<<<NB_LP, 512, 0, stream>>>(edge_index, flags, z4, lap_part, E);
    kE_lap_hist<<<NB_LP, 512, 0, stream>>>(edge_index, flags, z4, lap_part, E);

    kF_curvature<<<32, 256, 0, stream>>>(out, z4, lap_part, out + N3);
    kF_curvature<<<32, 256, 0, stream>>>(out, z4, lap_part, out + N3);
}

// Round 10
// 158.960 us; speedup vs baseline: 1.2560x; 1.2560x over previous
//
#include <hip/hip_runtime.h>
#include <math.h>

#define N_NODES 8192
#define N3      24576              // N_NODES * 3
#define WPR     256                // uint words per bitmask row (8192/32)
#define LR_C 0.01f
#define EPS_C 1e-6f
#define NJ 32                      // j-chunks in repulsion
#define NB_SC 64                   // corr-histogram blocks
#define RPB 64                     // rows per scan block
#define NB_SCAN 128                // N_NODES / RPB

// =============== K1: corr LDS-hist (blk 0-63) || edge pack (blk 64-191) =====
__global__ __launch_bounds__(512) void k1_corr_pack(
        const float* __restrict__ x0, const int* __restrict__ dist_idx,
        const float* __restrict__ dist_target, const int* __restrict__ edge_index,
        float* __restrict__ corr_part, unsigned int* __restrict__ packed,
        int K, int E) {
    __shared__ __align__(16) float smf[N3];          // 96 KiB
    int bid = blockIdx.x, tid = threadIdx.x;
    if (bid < NB_SC) {
        for (int t = tid; t < N3; t += 512) smf[t] = 0.f;
        __syncthreads();
        int per = (K + NB_SC - 1) / NB_SC;           // 1024
        int base = bid * per;
        for (int kk = tid; kk < per; kk += 512) {
            int k = base + kk;
            if (k >= K) break;
            int i = dist_idx[2 * k], j = dist_idx[2 * k + 1];
            float ax = x0[3 * i], ay = x0[3 * i + 1], az = x0[3 * i + 2];
            float bx = x0[3 * j], by = x0[3 * j + 1], bz = x0[3 * j + 2];
            float vx = ax - bx, vy = ay - by, vz = az - bz;
            float dist = sqrtf(vx * vx + vy * vy + vz * vz + 1e-12f);
            bool valid = (dist > EPS_C) && (i != j);
            float coef = valid ? (LR_C * 0.5f) * (dist - dist_target[k]) / dist
                               : 0.0f;
            if (coef != 0.0f) {
                float cx = coef * vx, cy = coef * vy, cz = coef * vz;
                atomicAdd(&smf[3 * i],     -cx);
                atomicAdd(&smf[3 * i + 1], -cy);
                atomicAdd(&smf[3 * i + 2], -cz);
                atomicAdd(&smf[3 * j],      cx);
                atomicAdd(&smf[3 * j + 1],  cy);
                atomicAdd(&smf[3 * j + 2],  cz);
            }
        }
        __syncthreads();
        float* dst = corr_part + (size_t)bid * N3;
        for (int t = tid; t < N3; t += 512) dst[t] = smf[t];
    } else {
        // pack: 128 blocks x 512 thr x 4 edges = 262144
        int g = (bid - NB_SC) * 512 + tid;           // uint4 index, < 65536
        const int4* a4 = (const int4*)edge_index;
        const int4* b4 = (const int4*)(edge_index + E);
        int4 a = a4[g];
        int4 b = b4[g];
        uint4 p;
        p.x = ((unsigned)min(max(a.x, 0), N_NODES - 1) << 13) |
               (unsigned)min(max(b.x, 0), N_NODES - 1);
        p.y = ((unsigned)min(max(a.y, 0), N_NODES - 1) << 13) |
               (unsigned)min(max(b.y, 0), N_NODES - 1);
        p.z = ((unsigned)min(max(a.z, 0), N_NODES - 1) << 13) |
               (unsigned)min(max(b.z, 0), N_NODES - 1);
        p.w = ((unsigned)min(max(a.w, 0), N_NODES - 1) << 13) |
               (unsigned)min(max(b.w, 0), N_NODES - 1);
        ((uint4*)packed)[g] = p;
    }
}

// =============== K3: bitmask scan + deg (blk 0-127) || x1 reduce (128-175) ==
// Scan block owns rows [bid*64, bid*64+64): builds A-rows and B(=A^T)-rows
// bitmasks in LDS over ALL edges (set-bit = free exact dedup), popcounts deg,
// writes masks to global. No device atomics anywhere.
__global__ __launch_bounds__(512) void k3_scan(
        const unsigned int* __restrict__ packed,
        unsigned int* __restrict__ Ag, unsigned int* __restrict__ Bg,
        int* __restrict__ deg,
        const float* __restrict__ pos, const float* __restrict__ corr_part,
        float* __restrict__ x1, int E) {
    __shared__ unsigned int mask[2 * RPB * WPR];     // 32768 words = 128 KiB
    int bid = blockIdx.x, tid = threadIdx.x;
    if (bid < NB_SCAN) {
        for (int w = tid; w < 2 * RPB * WPR; w += 512) mask[w] = 0u;
        __syncthreads();
        int base = bid * RPB;
        const uint4* p4 = (const uint4*)packed;
        int n4 = E >> 2;                             // 65536
        for (int it = tid; it < n4; it += 512) {
            uint4 v = p4[it];
            unsigned int vv[4] = { v.x, v.y, v.z, v.w };
            #pragma unroll
            for (int q = 0; q < 4; ++q) {
                int a = vv[q] >> 13;
                int b = vv[q] & (N_NODES - 1);
                int ra = a - base;
                if ((unsigned)ra < RPB)
                    atomicOr(&mask[ra * WPR + (b >> 5)], 1u << (b & 31));
                int rb = b - base;
                if ((unsigned)rb < RPB)
                    atomicOr(&mask[(RPB + rb) * WPR + (a >> 5)], 1u << (a & 31));
            }
        }
        __syncthreads();
        // degree: 8 threads per row
        {
            int r = tid >> 3, s = tid & 7;
            int cnt = 0;
            for (int w = s; w < WPR; w += 8) {
                cnt += __popc(mask[r * WPR + w]);
                cnt += __popc(mask[(RPB + r) * WPR + w]);
            }
            cnt += __shfl_down(cnt, 4, 8);
            cnt += __shfl_down(cnt, 2, 8);
            cnt += __shfl_down(cnt, 1, 8);
            if (s == 0) deg[base + r] = cnt;
        }
        // write masks to global (coalesced uint4)
        uint4* dstA = (uint4*)(Ag + (size_t)base * WPR);
        uint4* dstB = (uint4*)(Bg + (size_t)base * WPR);
        const uint4* sm4 = (const uint4*)mask;
        int q4 = RPB * WPR / 4;                      // 4096
        for (int w = tid; w < q4; w += 512) dstA[w] = sm4[w];
        for (int w = tid; w < q4; w += 512) dstB[w] = sm4[q4 + w];
    } else {
        int e = (bid - NB_SCAN) * 512 + tid;         // 48 blocks -> 24576
        float s = pos[e];
        #pragma unroll 8
        for (int q = 0; q < NB_SC; ++q) s += corr_part[(size_t)q * N3 + e];
        x1[e] = s;
    }
}

// =============== K4: repulsion (512 blocks x 256 thr, 2 rows/thread) ========
__global__ __launch_bounds__(256) void k4_rep(
        const float* __restrict__ x1, const float* __restrict__ min_dist,
        float4* __restrict__ rep_part) {
    __shared__ __align__(16) float4 pj[256];         // 4 KiB j-tile
    int bid = blockIdx.x, tid = threadIdx.x;
    int ic = bid >> 5;                               // 0..15 (512 rows each)
    int jc = bid & 31;                               // 0..31 (256 cols each)
    int jbase = jc << 8;
    {
        int j = jbase + tid;
        float a = x1[3 * j], b = x1[3 * j + 1], c = x1[3 * j + 2];
        pj[tid] = make_float4(a, b, c, a * a + b * b + c * c);
    }
    __syncthreads();
    int i0 = (ic << 9) + tid;
    int i1 = i0 + 256;
    float x0v = x1[3 * i0], y0v = x1[3 * i0 + 1], z0v = x1[3 * i0 + 2];
    float x1v = x1[3 * i1], y1v = x1[3 * i1 + 1], z1v = x1[3 * i1 + 2];
    float sq0 = x0v * x0v + y0v * y0v + z0v * z0v;
    float sq1 = x1v * x1v + y1v * y1v + z1v * z1v;
    float md = min_dist[0];
    const float c0 = 0.5f * LR_C;                    // 0.005
    float c1 = c0 * md;
    int di0 = i0 - jbase, di1 = i1 - jbase;          // self slots (may be OOR)
    float S0 = 0.f, ax0 = 0.f, ay0 = 0.f, az0 = 0.f;
    float S1 = 0.f, ax1 = 0.f, ay1 = 0.f, az1 = 0.f;
    #pragma unroll 4
    for (int jj = 0; jj < 256; ++jj) {
        float4 q = pj[jj];
        float dot0 = fmaf(x0v, q.x, fmaf(y0v, q.y, z0v * q.z));
        float d20 = fmaf(-2.0f, dot0, sq0 + q.w);
        float r0 = __builtin_amdgcn_rsqf(fmaxf(d20, 1e-12f));
        float w0 = fmaxf(fmaf(c1, r0, -c0), 0.0f);           // >0 iff d < md
        w0 = (d20 > 1e-12f && jj != di0) ? w0 : 0.0f;
        S0 += w0;
        ax0 = fmaf(w0, q.x, ax0); ay0 = fmaf(w0, q.y, ay0); az0 = fmaf(w0, q.z, az0);
        float dot1 = fmaf(x1v, q.x, fmaf(y1v, q.y, z1v * q.z));
        float d21 = fmaf(-2.0f, dot1, sq1 + q.w);
        float r1 = __builtin_amdgcn_rsqf(fmaxf(d21, 1e-12f));
        float w1 = fmaxf(fmaf(c1, r1, -c0), 0.0f);
        w1 = (d21 > 1e-12f && jj != di1) ? w1 : 0.0f;
        S1 += w1;
        ax1 = fmaf(w1, q.x, ax1); ay1 = fmaf(w1, q.y, ay1); az1 = fmaf(w1, q.z, az1);
    }
    rep_part[(size_t)jc * N_NODES + i0] = make_float4(ax0, ay0, az0, S0);
    rep_part[(size_t)jc * N_NODES + i1] = make_float4(ax1, ay1, az1, S1);
}

// =============== K5: finalize (256 blocks, 8 threads/row) ===================
__global__ __launch_bounds__(256) void k5_finalize(
        const float* __restrict__ x1, const float4* __restrict__ rep_part,
        const int* __restrict__ deg,
        float* __restrict__ out_x, float4* __restrict__ z4) {
    int gid = blockIdx.x * 256 + threadIdx.x;        // 65536
    int r = gid >> 3, s = gid & 7;
    float S = 0.f, ax = 0.f, ay = 0.f, az = 0.f;
    #pragma unroll
    for (int c = s; c < NJ; c += 8) {
        float4 q = rep_part[(size_t)c * N_NODES + r];
        ax += q.x; ay += q.y; az += q.z; S += q.w;
    }
    ax += __shfl_down(ax, 4, 8); ax += __shfl_down(ax, 2, 8); ax += __shfl_down(ax, 1, 8);
    ay += __shfl_down(ay, 4, 8); ay += __shfl_down(ay, 2, 8); ay += __shfl_down(ay, 1, 8);
    az += __shfl_down(az, 4, 8); az += __shfl_down(az, 2, 8); az += __shfl_down(az, 1, 8);
    S  += __shfl_down(S, 4, 8);  S  += __shfl_down(S, 2, 8);  S  += __shfl_down(S, 1, 8);
    if (s == 0) {
        float xi = x1[3 * r], yi = x1[3 * r + 1], zi = x1[3 * r + 2];
        float ox = xi + xi * S - ax;
        float oy = yi + yi * S - ay;
        float oz = zi + zi * S - az;
        out_x[3 * r] = ox; out_x[3 * r + 1] = oy; out_x[3 * r + 2] = oz;
        int d = deg[r];
        float dv = (d == 0) ? 0.0f : 1.0f / sqrtf((float)d + EPS_C);
        z4[r] = make_float4(dv * ox, dv * oy, dv * oz, dv);
    }
}

// =============== K6: laplacian gather + curvature (128 blocks) ==============
// Block owns rows [bid*64, ..+64): streams its own mask rows, gathers z4
// (L2-resident, 128 KiB), accumulates in LDS, writes curvature directly.
__global__ __launch_bounds__(512) void k6_lap_curv(
        const unsigned int* __restrict__ Ag, const unsigned int* __restrict__ Bg,
        const float4* __restrict__ z4, const float* __restrict__ out_x,
        float* __restrict__ out_curv) {
    __shared__ float acc[RPB][4];                    // 1 KiB
    int bid = blockIdx.x, tid = threadIdx.x;
    int base = bid * RPB;
    if (tid < RPB) { acc[tid][0] = 0.f; acc[tid][1] = 0.f; acc[tid][2] = 0.f; }
    __syncthreads();
    int nw = RPB * WPR;                              // 16384 words per mask
    for (int w = tid; w < nw; w += 512) {
        int r = w >> 8;                              // w / WPR
        int wi = w & (WPR - 1);
        unsigned int m = Ag[(size_t)base * WPR + w];
        while (m) {
            int bit = __ffs(m) - 1; m &= m - 1;
            float4 z = z4[wi * 32 + bit];
            atomicAdd(&acc[r][0], z.x);
            atomicAdd(&acc[r][1], z.y);
            atomicAdd(&acc[r][2], z.z);
        }
        m = Bg[(size_t)base * WPR + w];
        while (m) {
            int bit = __ffs(m) - 1; m &= m - 1;
            float4 z = z4[wi * 32 + bit];
            atomicAdd(&acc[r][0], z.x);
            atomicAdd(&acc[r][1], z.y);
            atomicAdd(&acc[r][2], z.z);
        }
    }
    __syncthreads();
    if (tid < RPB) {
        int r = base + tid;
        float dv = z4[r].w;
        float Lx = out_x[3 * r]     - dv * acc[tid][0];
        float Ly = out_x[3 * r + 1] - dv * acc[tid][1];
        float Lz = out_x[3 * r + 2] - dv * acc[tid][2];
        out_curv[r] = sqrtf(Lx * Lx + Ly * Ly + Lz * Lz + 1e-12f);
    }
}

extern "C" void kernel_launch(void* const* d_in, const int* in_sizes, int n_in,
                              void* d_out, int out_size, void* d_ws, size_t ws_size,
                              hipStream_t stream) {
    const float* positions   = (const float*)d_in[0];
    const int*   edge_index  = (const int*)d_in[1];
    const int*   dist_idx    = (const int*)d_in[2];
    const float* dist_target = (const float*)d_in[3];
    const float* min_dist    = (const float*)d_in[4];
    float* out = (float*)d_out;

    const int E = in_sizes[1] / 2;   // 262144
    const int K = in_sizes[2] / 2;   // 65536

    // ---- workspace layout (16B aligned, no overlays; ws is ~256 MB) ----
    char* ws = (char*)d_ws;
    const size_t X1_OFF   = 0;                                   //  96 KiB
    const size_t Z4_OFF   = X1_OFF   + (size_t)N3 * 4;           // 128 KiB
    const size_t DEG_OFF  = Z4_OFF   + (size_t)N_NODES * 16;     //  32 KiB
    const size_t PACK_OFF = DEG_OFF  + (size_t)N_NODES * 4;      //   1 MiB
    const size_t CORR_OFF = PACK_OFF + (size_t)E * 4;            //   6 MiB
    const size_t REP_OFF  = CORR_OFF + (size_t)NB_SC * N3 * 4;   //   4 MiB
    const size_t AG_OFF   = REP_OFF  + (size_t)NJ * N_NODES * 16;//   8 MiB
    const size_t BG_OFF   = AG_OFF   + (size_t)N_NODES * WPR * 4;//   8 MiB

    float* x1            = (float*)(ws + X1_OFF);
    float4* z4           = (float4*)(ws + Z4_OFF);
    int*   deg           = (int*)(ws + DEG_OFF);
    unsigned int* packed = (unsigned int*)(ws + PACK_OFF);
    float* corr_part     = (float*)(ws + CORR_OFF);
    float4* rep_part     = (float4*)(ws + REP_OFF);
    unsigned int* Ag     = (unsigned int*)(ws + AG_OFF);
    unsigned int* Bg     = (unsigned int*)(ws + BG_OFF);

    k1_corr_pack<<<NB_SC + 128, 512, 0, stream>>>(
        positions, dist_idx, dist_target, edge_index, corr_part, packed, K, E);

    k3_scan<<<NB_SCAN + 48, 512, 0, stream>>>(
        packed, Ag, Bg, deg, positions, corr_part, x1, E);

    k4_rep<<<512, 256, 0, stream>>>(x1, min_dist, rep_part);

    k5_finalize<<<256, 256, 0, stream>>>(x1, rep_part, deg, out, z4);

    k6_lap_curv<<<NB_SCAN, 512, 0, stream>>>(Ag, Bg, z4, out, out + N3);
}